// Round 7
// baseline (134.446 us; speedup 1.0000x reference)
//
#include <hip/hip_runtime.h>
#include <math.h>

// ---- problem constants ----
constexpr int cB   = 64;
constexpr int cC   = 20;
constexpr int cNA  = 5;
constexpr int cH   = 19;
constexpr int cW   = 19;
constexpr int cT   = 50;
constexpr int cNB  = cB * cC;          // 1280
constexpr int cHW  = cH * cW;          // 361
constexpr int cA4  = cNA * cHW;        // 1805
constexpr int cCH  = cNA * 6;          // 30 channels
constexpr long cNTOT = (long)cNB * cA4; // 2,310,400
constexpr int cMAIN_BLOCKS = cNB * 2;  // 2560
constexpr int cCLS_BLOCKS  = cB * cNA; // 320

// ---- anchors: compile-time (match setup_inputs exactly) ----
__device__ __constant__ float cAW[cNA]   = {1.3221f, 3.19275f, 5.05587f, 9.47112f, 11.2364f};
__device__ __constant__ float cAH[cNA]   = {1.73145f, 4.00944f, 8.09892f, 4.84053f, 10.0071f};
__device__ __constant__ float cAREA[cNA] = {2.28930345f, 12.80114796f, 40.94706183f, 45.84455262f, 112.44377644f};
__device__ __constant__ float cLNAW[cNA] = {0.27920469f, 1.16088088f, 1.62060702f, 2.24822684f, 2.41915174f};
__device__ __constant__ float cLNAH[cNA] = {0.54896100f, 1.38865236f, 2.09173157f, 1.57701337f, 2.30329495f};

// ---- workspace layout (bytes) ----
// part1: 2560 blocks x 3 doubles (bce, sq, sconf) — written unconditionally
// cnt:   completion counter (zeroed by k_main block 0)
// part2: 320 blocks x 2 doubles (nll, nsel)
constexpr size_t OFF_P1  = 0;
constexpr size_t OFF_CNT = (size_t)cMAIN_BLOCKS * 3 * 8;          // 61440
constexpr size_t OFF_P2  = OFF_CNT + 64;

// ---- fast transcendentals (raw HW ops) ----
__device__ __forceinline__ float fexp(float x) {
    return __builtin_amdgcn_exp2f(x * 1.4426950408889634f);
}
__device__ __forceinline__ float flog(float x) {
    return __builtin_amdgcn_logf(x) * 0.6931471805599453f;
}
__device__ __forceinline__ float frcp(float x) { return __builtin_amdgcn_rcpf(x); }
__device__ __forceinline__ float fsigmoid(float x) { return frcp(1.0f + fexp(-x)); }

// ---- packed f16 helpers ----
typedef _Float16 h2 __attribute__((ext_vector_type(2)));
union HU { unsigned u; h2 h; };
__device__ __forceinline__ unsigned splat2(float v) {
    HU x; _Float16 f = (_Float16)v; x.h[0] = f; x.h[1] = f; return x.u;
}
// boxes pre-scaled by sqrt(1.6): inner test is pk_fma(iw,ih,-0.6ga) > 0.6pa
constexpr float cS = 1.2649110640673518f;   // sqrt(1.6)

// =====================================================================
// K1: fused prep + per-cell losses. 2 blocks per nb, 4 cells/thread.
// Writes per-block partials (no global zero-init needed anywhere).
// =====================================================================
__launch_bounds__(256)
__global__ void k_main(const float* __restrict__ outp, const float* __restrict__ target,
                       double* __restrict__ part1, int* __restrict__ cnt) {
    __shared__ int s_win[cA4];                       // per-nb winner (LDS only)
    __shared__ __align__(16) unsigned s_box[cT][8];  // scaled f16x2: l,r,t,b,g
    __shared__ __align__(16) float4 s_gt[cT];        // f32 gx,gy,gw,gh
    __shared__ double s_red[3][4];
    const int tid  = threadIdx.x;
    const int nb   = blockIdx.x >> 1;
    const int half = blockIdx.x & 1;
    const int base = (half << 10) + tid;             // 0..1023 / 1024..2047
    const float* obase = outp + (size_t)nb * (cCH * cHW);

    if (blockIdx.x == 0 && tid == 0) *cnt = 0;       // for K2's last-block gate

    for (int k = tid; k < cA4; k += 256) s_win[k] = -1;
    __syncthreads();

    // ---- prep (wave 0 only; both halves duplicate — LDS-local) ----
    if (tid < 64) {
        const int t = tid;
        float xr = 1.f, yr = 0.f, wr = 0.f, hr = 0.f;
        if (t < cT) {
            const float* tg = target + (size_t)nb * (cT * 5) + t * 5;
            xr = tg[1]; yr = tg[2]; wr = tg[3]; hr = tg[4];
        }
        unsigned long long nz = __ballot(xr != 0.0f);
        if (t < cT) {
            unsigned long long below = (2ull << t) - 1ull;
            bool valid = ((~nz) & below) == 0ull;
            float gx = xr * (float)cW, gy = yr * (float)cH;
            float gw = wr * (float)cW, gh = hr * (float)cH;
            s_gt[t] = make_float4(gx, gy, gw, gh);
            if (valid) {
                s_box[t][0] = splat2(cS * (gx - 0.5f * gw));
                s_box[t][1] = splat2(cS * (gx + 0.5f * gw));
                s_box[t][2] = splat2(cS * (gy - 0.5f * gh));
                s_box[t][3] = splat2(cS * (gy + 0.5f * gh));
                s_box[t][4] = splat2(-0.6f * (gw * gh));
                float garea = gw * gh;
                float best = -1.0f; int bn = 0;
                for (int n = 0; n < cNA; ++n) {
                    float inter = fminf(gw, cAW[n]) * fminf(gh, cAH[n]);
                    float uni   = garea + cAREA[n] - inter;
                    float r = inter / fmaxf(uni, 1e-12f);
                    if (r > best) { best = r; bn = n; }
                }
                int cell = bn * cHW + (int)gy * cW + (int)gx;
                atomicMax(&s_win[cell], t);
            } else {                              // degenerate: inter == 0
                s_box[t][0] = splat2(1e4f);  s_box[t][1] = splat2(-1e4f);
                s_box[t][2] = splat2(1e4f);  s_box[t][3] = splat2(-1e4f);
                s_box[t][4] = splat2(0.0f);
            }
        }
    }
    __syncthreads();

    // ---- Phase A: boxes + bce/sq/tconf ----
    h2 pl2[2], pr2[2], pt2[2], pb2[2], ov2[2], pa06h[2];
    float conf[4], tcf[4];
    unsigned wbits = 0;
    float bce = 0.0f, sq = 0.0f;
    const h2 z2 = { (_Float16)0.0f, (_Float16)0.0f };

    #pragma unroll
    for (int u = 0; u < 4; ++u) {
        int cell = base + (u << 8);
        bool a_  = cell < cA4;
        int cc   = a_ ? cell : (cA4 - 1);
        int na   = cc / cHW;
        int rem  = cc - na * cHW;
        int j    = rem / cW;
        int i    = rem - j * cW;
        const float* ob = obase + (size_t)(na * 6) * cHW + rem;
        float xl = ob[0], yl = ob[cHW], wl = ob[2*cHW], hl = ob[3*cHW], cl = ob[4*cHW];
        float aw = cAW[na], ah = cAH[na];
        float x  = fsigmoid(xl), y = fsigmoid(yl), cf = fsigmoid(cl);
        float px = x + (float)i, py = y + (float)j;
        float pw = fexp(wl) * aw, ph = fexp(hl) * ah;
        float l0 = px - 0.5f*pw, r0 = px + 0.5f*pw;
        float t0 = py - 0.5f*ph, b0 = py + 0.5f*ph;
        float pa = pw * ph;
        int p = u >> 1, s = u & 1;
        pl2[p][s] = (_Float16)(cS * l0);  pr2[p][s] = (_Float16)(cS * r0);
        pt2[p][s] = (_Float16)(cS * t0);  pb2[p][s] = (_Float16)(cS * b0);
        pa06h[p][s] = (_Float16)(0.6f * pa);
        ov2[p][s] = (_Float16)0.0f;
        conf[u] = cf; tcf[u] = 0.0f;

        float tx = 0.5f, ty = 0.5f, tw = 0.0f, th = 0.0f;
        int wt = s_win[cc];
        bool wfl = (wt >= 0) && a_;
        if (wfl) {
            wbits |= (1u << u);
            float4 g = s_gt[wt];
            float gx = g.x, gy = g.y, gw = g.z, gh = g.w;
            tx = gx - (float)i; ty = gy - (float)j;
            tw = flog(fmaxf(gw, 1e-12f)) - cLNAW[na];
            th = flog(fmaxf(gh, 1e-12f)) - cLNAH[na];
            float iw = fminf(r0, gx + 0.5f*gw) - fmaxf(l0, gx - 0.5f*gw);
            float ih = fminf(b0, gy + 0.5f*gh) - fmaxf(t0, gy - 0.5f*gh);
            iw = fmaxf(iw, 0.0f); ih = fmaxf(ih, 0.0f);
            float inter = iw * ih;
            float uni   = gw*gh + pa - inter;
            tcf[u] = inter * frcp(fmaxf(uni, 1e-12f));
        }
        if (a_) {
            float pc = fminf(fmaxf(x, 1e-7f), 1.0f - 1e-7f);
            bce += -(tx * flog(pc) + (1.0f - tx) * flog(1.0f - pc));
            pc = fminf(fmaxf(y, 1e-7f), 1.0f - 1e-7f);
            bce += -(ty * flog(pc) + (1.0f - ty) * flog(1.0f - pc));
            float dw = wl - tw, dh = hl - th;
            sq += dw*dw + dh*dh;
        }
    }

    // ---- Phase B: any-target IoU > 0.6, packed f16, pre-scaled boxes ----
    #pragma unroll 10
    for (int t = 0; t < cT; ++t) {
        uint4 bx = *(const uint4*)&s_box[t][0];
        unsigned gv = s_box[t][4];
        HU a, b, c, d, e;
        a.u = bx.x; b.u = bx.y; c.u = bx.z; d.u = bx.w; e.u = gv;
        #pragma unroll
        for (int p = 0; p < 2; ++p) {
            h2 iw = __builtin_elementwise_min(pr2[p], b.h) - __builtin_elementwise_max(pl2[p], a.h);
            h2 ih = __builtin_elementwise_min(pb2[p], d.h) - __builtin_elementwise_max(pt2[p], c.h);
            iw = __builtin_elementwise_max(iw, z2);
            ih = __builtin_elementwise_max(ih, z2);
            ov2[p] = __builtin_elementwise_max(ov2[p], iw * ih + e.h);  // v_pk_fma
        }
    }

    // ---- epilogue: conf loss ----
    float sc = 0.0f;
    #pragma unroll
    for (int u = 0; u < 4; ++u) {
        int cell = base + (u << 8);
        if (cell >= cA4) continue;
        int p = u >> 1, s = u & 1;
        bool wfl  = (wbits >> u) & 1;
        bool over = ov2[p][s] > pa06h[p][s];
        float cm  = wfl ? 1.0f : (over ? 0.0f : 1.0f);
        float d   = (conf[u] - tcf[u]) * cm;
        sc += d * d;
    }

    // ---- block reduction -> per-block partial slots (no atomics) ----
    double v0 = (double)bce, v1 = (double)sq, v2 = (double)sc;
    for (int off = 32; off > 0; off >>= 1) {
        v0 += __shfl_down(v0, off);
        v1 += __shfl_down(v1, off);
        v2 += __shfl_down(v2, off);
    }
    int lane = tid & 63, wid = tid >> 6;
    if (lane == 0) { s_red[0][wid] = v0; s_red[1][wid] = v1; s_red[2][wid] = v2; }
    __syncthreads();
    if (tid == 0) {
        part1[(size_t)blockIdx.x * 3 + 0] = s_red[0][0] + s_red[0][1] + s_red[0][2] + s_red[0][3];
        part1[(size_t)blockIdx.x * 3 + 1] = s_red[1][0] + s_red[1][1] + s_red[1][2] + s_red[1][3];
        part1[(size_t)blockIdx.x * 3 + 2] = s_red[2][0] + s_red[2][1] + s_red[2][2] + s_red[2][3];
    }
}

// =====================================================================
// K2: class NLL, self-contained. Block = (b, na); thread = rem.
// Recomputes winners for this slab in LDS (wave-per-class), then
// coalesced 20-logit lse per row. Finalize fused into last block.
// =====================================================================
__launch_bounds__(384)
__global__ void k_cls(const float* __restrict__ outp, const float* __restrict__ target,
                      const double* __restrict__ part1, double* __restrict__ part2,
                      int* __restrict__ cnt, float* __restrict__ out) {
    __shared__ int s_win[cC * cHW];                  // winner t per (class, rem)
    __shared__ double s_red[2][6];
    __shared__ double s_fin[5][6];
    __shared__ int s_last;
    const int tid  = threadIdx.x;
    const int wave = tid >> 6;
    const int lane = tid & 63;
    const int b    = blockIdx.x / cNA;
    const int na   = blockIdx.x - b * cNA;

    for (int k = tid; k < cC * cHW; k += 384) s_win[k] = -1;
    __syncthreads();

    // winners: wave w handles classes w, w+6, ... (ballot validity per class row)
    for (int c = wave; c < cC; c += 6) {
        const float* tg = target + (size_t)(b * cC + c) * (cT * 5);
        float xr = 1.f, yr = 0.f, wr = 0.f, hr = 0.f;
        if (lane < cT) { xr = tg[lane*5+1]; yr = tg[lane*5+2]; wr = tg[lane*5+3]; hr = tg[lane*5+4]; }
        unsigned long long nz = __ballot(xr != 0.0f);
        if (lane < cT) {
            unsigned long long below = (2ull << lane) - 1ull;
            bool valid = ((~nz) & below) == 0ull;
            if (valid) {
                float gx = xr * (float)cW, gy = yr * (float)cH;
                float gw = wr * (float)cW, gh = hr * (float)cH;
                float garea = gw * gh;
                float best = -1.0f; int bn = 0;
                for (int n = 0; n < cNA; ++n) {
                    float inter = fminf(gw, cAW[n]) * fminf(gh, cAH[n]);
                    float uni   = garea + cAREA[n] - inter;
                    float r = inter / fmaxf(uni, 1e-12f);
                    if (r > best) { best = r; bn = n; }
                }
                if (bn == na)
                    atomicMax(&s_win[c * cHW + (int)gy * cW + (int)gx], lane);
            }
        }
    }
    __syncthreads();

    double nll = 0.0, ns = 0.0;
    if (tid < cHW) {
        const int rem = tid;
        int cntc = 0, selc = -1, selt = -1;
        #pragma unroll
        for (int c = 0; c < cC; ++c) {
            int wv = s_win[c * cHW + rem];
            if (wv >= 0) { cntc++; selc = c; selt = wv; }
        }
        if (cntc == 1) {
            const float* ob = outp + ((size_t)(b * cC) * cCH + na * 6 + 5) * cHW + rem;
            float l[cC]; float m = -1e30f;
            #pragma unroll
            for (int c = 0; c < cC; ++c) {
                l[c] = ob[(size_t)c * (cCH * cHW)];
                m = fmaxf(m, l[c]);
            }
            float s = 0.0f;
            #pragma unroll
            for (int c = 0; c < cC; ++c) s += fexp(l[c] - m);
            float lse = m + flog(s);
            int label = (int)target[((size_t)(b * cC + selc) * cT + selt) * 5];
            nll = (double)(lse - l[label]);
            ns  = 1.0;
        }
    }
    for (int off = 32; off > 0; off >>= 1) {
        nll += __shfl_down(nll, off);
        ns  += __shfl_down(ns, off);
    }
    if (lane == 0) { s_red[0][wave] = nll; s_red[1][wave] = ns; }
    __syncthreads();
    if (tid == 0) {
        double a0 = 0.0, a1 = 0.0;
        #pragma unroll
        for (int w = 0; w < 6; ++w) { a0 += s_red[0][w]; a1 += s_red[1][w]; }
        part2[(size_t)blockIdx.x * 2 + 0] = a0;
        part2[(size_t)blockIdx.x * 2 + 1] = a1;
        __threadfence();                                  // release
        s_last = (atomicAdd(cnt, 1) == cCLS_BLOCKS - 1);
    }
    __syncthreads();

    if (s_last) {
        __threadfence();                                  // acquire
        double v[5] = {0.0, 0.0, 0.0, 0.0, 0.0};
        for (int k = tid; k < cMAIN_BLOCKS; k += 384) {   // K1 partials: plain loads
            v[0] += part1[(size_t)k * 3 + 0];             // (kernel-boundary coherence)
            v[1] += part1[(size_t)k * 3 + 1];
            v[2] += part1[(size_t)k * 3 + 2];
        }
        for (int k = tid; k < cCLS_BLOCKS; k += 384) {    // K2 partials: atomic reads
            v[3] += atomicAdd(&part2[(size_t)k * 2 + 0], 0.0);
            v[4] += atomicAdd(&part2[(size_t)k * 2 + 1], 0.0);
        }
        #pragma unroll
        for (int j = 0; j < 5; ++j)
            for (int off = 32; off > 0; off >>= 1) v[j] += __shfl_down(v[j], off);
        if (lane == 0) {
            #pragma unroll
            for (int j = 0; j < 5; ++j) s_fin[j][wave] = v[j];
        }
        __syncthreads();
        if (tid == 0) {
            double s[5];
            #pragma unroll
            for (int j = 0; j < 5; ++j) {
                double a = 0.0;
                #pragma unroll
                for (int w = 0; w < 6; ++w) a += s_fin[j][w];
                s[j] = a;
            }
            double Ninv = 1.0 / (double)cNTOT;
            double loss = s[0] * Ninv            // loss_x + loss_y
                        + 0.5 * s[1] * Ninv      // loss_w + loss_h
                        + 0.5 * s[2] * Ninv      // loss_conf
                        + s[3] / fmax(s[4], 1.0);// loss_cls
            out[0] = (float)loss;
        }
    }
}

extern "C" void kernel_launch(void* const* d_in, const int* in_sizes, int n_in,
                              void* d_out, int out_size, void* d_ws, size_t ws_size,
                              hipStream_t stream) {
    const float* output = (const float*)d_in[0];
    const float* target = (const float*)d_in[1];
    char* ws = (char*)d_ws;
    double* part1 = (double*)(ws + OFF_P1);
    int*    cnt   = (int*)   (ws + OFF_CNT);
    double* part2 = (double*)(ws + OFF_P2);

    k_main<<<cMAIN_BLOCKS, 256, 0, stream>>>(output, target, part1, cnt);
    k_cls<<<cCLS_BLOCKS, 384, 0, stream>>>(output, target, part1, part2, cnt, (float*)d_out);
}

// Round 8
// 133.757 us; speedup vs baseline: 1.0051x; 1.0051x over previous
//
#include <hip/hip_runtime.h>
#include <math.h>

// ---- problem constants ----
constexpr int cB   = 64;
constexpr int cC   = 20;
constexpr int cNA  = 5;
constexpr int cH   = 19;
constexpr int cW   = 19;
constexpr int cT   = 50;
constexpr int cNB  = cB * cC;          // 1280
constexpr int cHW  = cH * cW;          // 361
constexpr int cA4  = cNA * cHW;        // 1805
constexpr int cCH  = cNA * 6;          // 30 channels
constexpr long cNTOT = (long)cNB * cA4; // 2,310,400
constexpr int cCLS_BLOCKS = cB * cNA * 2;  // 640

// ---- anchors: compile-time (match setup_inputs exactly) ----
__device__ __constant__ float cAW[cNA]   = {1.3221f, 3.19275f, 5.05587f, 9.47112f, 11.2364f};
__device__ __constant__ float cAH[cNA]   = {1.73145f, 4.00944f, 8.09892f, 4.84053f, 10.0071f};
__device__ __constant__ float cAREA[cNA] = {2.28930345f, 12.80114796f, 40.94706183f, 45.84455262f, 112.44377644f};
__device__ __constant__ float cLNAW[cNA] = {0.27920469f, 1.16088088f, 1.62060702f, 2.24822684f, 2.41915174f};
__device__ __constant__ float cLNAH[cNA] = {0.54896100f, 1.38865236f, 2.09173157f, 1.57701337f, 2.30329495f};

// ---- workspace layout (bytes) ----
constexpr int ACC_BANKS = 64;
constexpr size_t OFF_CNT = 2560;                // after 5*64 doubles
constexpr size_t OFF_ROW = 4096;                // rowenc: cB*cA4 ints = 462080 B
constexpr size_t ZERO_BYTES = OFF_ROW + (size_t)cB * cA4 * 4;

// ---- fast transcendentals (raw HW ops) ----
__device__ __forceinline__ float fexp(float x) {
    return __builtin_amdgcn_exp2f(x * 1.4426950408889634f);
}
__device__ __forceinline__ float flog(float x) {
    return __builtin_amdgcn_logf(x) * 0.6931471805599453f;
}
__device__ __forceinline__ float frcp(float x) { return __builtin_amdgcn_rcpf(x); }
__device__ __forceinline__ float fsigmoid(float x) { return frcp(1.0f + fexp(-x)); }

// ---- packed f16 helpers ----
typedef _Float16 h2 __attribute__((ext_vector_type(2)));
union HU { unsigned u; h2 h; };
__device__ __forceinline__ unsigned splat2(float v) {
    HU x; _Float16 f = (_Float16)v; x.h[0] = f; x.h[1] = f; return x.u;
}
// boxes pre-scaled by sqrt(1.6): inner test is pk_fma(iw,ih,-0.6ga) > 0.6pa
constexpr float cS = 1.2649110640673518f;   // sqrt(1.6)

// =====================================================================
// K1: fused prep + per-cell losses. ONE 512-thread block per nb,
// 4 cells/thread. 8 waves/block; launch_bounds(512,8) -> 4 blocks/CU.
// =====================================================================
__launch_bounds__(512, 8)
__global__ void k_main(const float* __restrict__ outp, const float* __restrict__ target,
                       int* __restrict__ rowenc, double* __restrict__ acc) {
    __shared__ int s_win[cA4];                       // per-nb winner (LDS only)
    __shared__ int s_tc[cT];                         // winner cell per target (-1 invalid)
    __shared__ __align__(16) unsigned s_box[cT][8];  // scaled f16x2: l,r,t,b,g
    __shared__ __align__(16) float4 s_gt[cT];        // f32 gx,gy,gw,gh
    __shared__ double s_red[3][8];
    const int tid = threadIdx.x;
    const int nb  = blockIdx.x;
    const int b_  = nb / cC;
    const int c_  = nb - b_ * cC;
    const float* obase = outp + (size_t)nb * (cCH * cHW);

    for (int k = tid; k < cA4; k += 512) s_win[k] = -1;
    __syncthreads();

    // ---- prep (wave 0 only) ----
    if (tid < 64) {
        const int t = tid;
        float xr = 1.f, yr = 0.f, wr = 0.f, hr = 0.f;
        if (t < cT) {
            const float* tg = target + (size_t)nb * (cT * 5) + t * 5;
            xr = tg[1]; yr = tg[2]; wr = tg[3]; hr = tg[4];
        }
        unsigned long long nz = __ballot(xr != 0.0f);
        if (t < cT) {
            unsigned long long below = (2ull << t) - 1ull;
            bool valid = ((~nz) & below) == 0ull;
            float gx = xr * (float)cW, gy = yr * (float)cH;
            float gw = wr * (float)cW, gh = hr * (float)cH;
            s_gt[t] = make_float4(gx, gy, gw, gh);
            if (valid) {
                s_box[t][0] = splat2(cS * (gx - 0.5f * gw));
                s_box[t][1] = splat2(cS * (gx + 0.5f * gw));
                s_box[t][2] = splat2(cS * (gy - 0.5f * gh));
                s_box[t][3] = splat2(cS * (gy + 0.5f * gh));
                s_box[t][4] = splat2(-0.6f * (gw * gh));
                float garea = gw * gh;
                float best = -1.0f; int bn = 0;
                for (int n = 0; n < cNA; ++n) {
                    float inter = fminf(gw, cAW[n]) * fminf(gh, cAH[n]);
                    float uni   = garea + cAREA[n] - inter;
                    float r = inter / fmaxf(uni, 1e-12f);
                    if (r > best) { best = r; bn = n; }
                }
                int cell = bn * cHW + (int)gy * cW + (int)gx;
                s_tc[t] = cell;
                atomicMax(&s_win[cell], t);
            } else {                              // degenerate: inter == 0
                s_box[t][0] = splat2(1e4f);  s_box[t][1] = splat2(-1e4f);
                s_box[t][2] = splat2(1e4f);  s_box[t][3] = splat2(-1e4f);
                s_box[t][4] = splat2(0.0f);
                s_tc[t] = -1;
            }
        }
    }
    __syncthreads();
    // rowenc: one atomic per winning target
    if (tid < cT) {
        int cell = s_tc[tid];
        if (cell >= 0 && s_win[cell] == tid)
            atomicAdd(&rowenc[b_ * cA4 + cell], (1 << 10) | (c_ * cT + tid));
    }

    // ---- Phase A: boxes + bce/sq/tconf ----
    h2 pl2[2], pr2[2], pt2[2], pb2[2], ov2[2], pa06h[2];
    float conf[4], tcf[4];
    unsigned wbits = 0;
    float bce = 0.0f, sq = 0.0f;
    const h2 z2 = { (_Float16)0.0f, (_Float16)0.0f };

    #pragma unroll
    for (int u = 0; u < 4; ++u) {
        int cell = tid + (u << 9);
        bool a_  = cell < cA4;
        int cc   = a_ ? cell : (cA4 - 1);
        int na   = cc / cHW;
        int rem  = cc - na * cHW;
        int j    = rem / cW;
        int i    = rem - j * cW;
        const float* ob = obase + (size_t)(na * 6) * cHW + rem;
        float xl = ob[0], yl = ob[cHW], wl = ob[2*cHW], hl = ob[3*cHW], cl = ob[4*cHW];
        float aw = cAW[na], ah = cAH[na];
        float x  = fsigmoid(xl), y = fsigmoid(yl), cf = fsigmoid(cl);
        float px = x + (float)i, py = y + (float)j;
        float pw = fexp(wl) * aw, ph = fexp(hl) * ah;
        float l0 = px - 0.5f*pw, r0 = px + 0.5f*pw;
        float t0 = py - 0.5f*ph, b0 = py + 0.5f*ph;
        float pa = pw * ph;
        int p = u >> 1, s = u & 1;
        pl2[p][s] = (_Float16)(cS * l0);  pr2[p][s] = (_Float16)(cS * r0);
        pt2[p][s] = (_Float16)(cS * t0);  pb2[p][s] = (_Float16)(cS * b0);
        pa06h[p][s] = (_Float16)(0.6f * pa);
        ov2[p][s] = (_Float16)0.0f;
        conf[u] = cf; tcf[u] = 0.0f;

        float tx = 0.5f, ty = 0.5f, tw = 0.0f, th = 0.0f;
        int wt = s_win[cc];
        bool wfl = (wt >= 0) && a_;
        if (wfl) {
            wbits |= (1u << u);
            float4 g = s_gt[wt];
            float gx = g.x, gy = g.y, gw = g.z, gh = g.w;
            tx = gx - (float)i; ty = gy - (float)j;
            tw = flog(fmaxf(gw, 1e-12f)) - cLNAW[na];
            th = flog(fmaxf(gh, 1e-12f)) - cLNAH[na];
            float iw = fminf(r0, gx + 0.5f*gw) - fmaxf(l0, gx - 0.5f*gw);
            float ih = fminf(b0, gy + 0.5f*gh) - fmaxf(t0, gy - 0.5f*gh);
            iw = fmaxf(iw, 0.0f); ih = fmaxf(ih, 0.0f);
            float inter = iw * ih;
            float uni   = gw*gh + pa - inter;
            tcf[u] = inter * frcp(fmaxf(uni, 1e-12f));
        }
        if (a_) {
            float pc = fminf(fmaxf(x, 1e-7f), 1.0f - 1e-7f);
            bce += -(tx * flog(pc) + (1.0f - tx) * flog(1.0f - pc));
            pc = fminf(fmaxf(y, 1e-7f), 1.0f - 1e-7f);
            bce += -(ty * flog(pc) + (1.0f - ty) * flog(1.0f - pc));
            float dw = wl - tw, dh = hl - th;
            sq += dw*dw + dh*dh;
        }
    }

    // ---- Phase B: any-target IoU > 0.6, packed f16, pre-scaled boxes ----
    #pragma unroll 10
    for (int t = 0; t < cT; ++t) {
        uint4 bx = *(const uint4*)&s_box[t][0];
        unsigned gv = s_box[t][4];
        HU a, b, c, d, e;
        a.u = bx.x; b.u = bx.y; c.u = bx.z; d.u = bx.w; e.u = gv;
        #pragma unroll
        for (int p = 0; p < 2; ++p) {
            h2 iw = __builtin_elementwise_min(pr2[p], b.h) - __builtin_elementwise_max(pl2[p], a.h);
            h2 ih = __builtin_elementwise_min(pb2[p], d.h) - __builtin_elementwise_max(pt2[p], c.h);
            iw = __builtin_elementwise_max(iw, z2);
            ih = __builtin_elementwise_max(ih, z2);
            ov2[p] = __builtin_elementwise_max(ov2[p], iw * ih + e.h);  // v_pk_fma
        }
    }

    // ---- epilogue: conf loss ----
    float sc = 0.0f;
    #pragma unroll
    for (int u = 0; u < 4; ++u) {
        int cell = tid + (u << 9);
        if (cell >= cA4) continue;
        int p = u >> 1, s = u & 1;
        bool wfl  = (wbits >> u) & 1;
        bool over = ov2[p][s] > pa06h[p][s];
        float cm  = wfl ? 1.0f : (over ? 0.0f : 1.0f);
        float d   = (conf[u] - tcf[u]) * cm;
        sc += d * d;
    }

    // ---- block reduction -> banked double atomics ----
    double v0 = (double)bce, v1 = (double)sq, v2 = (double)sc;
    for (int off = 32; off > 0; off >>= 1) {
        v0 += __shfl_down(v0, off);
        v1 += __shfl_down(v1, off);
        v2 += __shfl_down(v2, off);
    }
    int lane = tid & 63, wid = tid >> 6;
    if (lane == 0) { s_red[0][wid] = v0; s_red[1][wid] = v1; s_red[2][wid] = v2; }
    __syncthreads();
    if (tid == 0) {
        double a0 = 0.0, a1 = 0.0, a2 = 0.0;
        #pragma unroll
        for (int w = 0; w < 8; ++w) { a0 += s_red[0][w]; a1 += s_red[1][w]; a2 += s_red[2][w]; }
        int bank = nb & (ACC_BANKS - 1);
        atomicAdd(&acc[0*ACC_BANKS + bank], a0);
        atomicAdd(&acc[1*ACC_BANKS + bank], a1);
        atomicAdd(&acc[2*ACC_BANKS + bank], a2);
    }
}

// =====================================================================
// K2: class NLL via rowenc (1 load/row). Block = (b, na, half); 192 thr.
// Unconditional coalesced 20-logit lse; rowenc picks numerator.
// Fused finalization in the last block.
// =====================================================================
__launch_bounds__(192)
__global__ void k_cls(const float* __restrict__ outp, const float* __restrict__ target,
                      const int* __restrict__ rowenc, double* __restrict__ acc,
                      int* __restrict__ cnt, float* __restrict__ out) {
    __shared__ double s_red[2][3];
    __shared__ int s_last;
    const int tid  = threadIdx.x;
    const int blk  = blockIdx.x;
    const int b    = blk / (cNA * 2);
    const int r2   = blk - b * (cNA * 2);
    const int na   = r2 >> 1;
    const int half = r2 & 1;
    const int rem  = half * 192 + tid;
    double nll = 0.0, ns = 0.0;
    if (rem < cHW) {
        const float* ob = outp + ((size_t)(b * cC) * cCH + na * 6 + 5) * cHW + rem;
        float l[cC]; float m = -1e30f;
        #pragma unroll
        for (int c = 0; c < cC; ++c) {
            l[c] = ob[(size_t)c * (cCH * cHW)];
            m = fmaxf(m, l[c]);
        }
        float s = 0.0f;
        #pragma unroll
        for (int c = 0; c < cC; ++c) s += fexp(l[c] - m);
        float lse = m + flog(s);
        int v = rowenc[b * cA4 + na * cHW + rem];
        if ((v >> 10) == 1) {                 // exactly one class set
            int payload = v & 1023;
            int selc = payload / cT;
            int selt = payload - selc * cT;
            int label = (int)target[((size_t)(b * cC + selc) * cT + selt) * 5];
            nll = (double)(lse - l[label]);
            ns  = 1.0;
        }
    }
    for (int off = 32; off > 0; off >>= 1) {
        nll += __shfl_down(nll, off);
        ns  += __shfl_down(ns, off);
    }
    int lane = tid & 63, wid = tid >> 6;
    if (lane == 0) { s_red[0][wid] = nll; s_red[1][wid] = ns; }
    __syncthreads();
    if (tid == 0) {
        double a0 = s_red[0][0] + s_red[0][1] + s_red[0][2];
        double a1 = s_red[1][0] + s_red[1][1] + s_red[1][2];
        int bank = blk & (ACC_BANKS - 1);
        atomicAdd(&acc[3*ACC_BANKS + bank], a0);
        atomicAdd(&acc[4*ACC_BANKS + bank], a1);
        __threadfence();                                  // release
        s_last = (atomicAdd(cnt, 1) == cCLS_BLOCKS - 1);
    }
    __syncthreads();
    if (s_last && tid < 64) {
        __threadfence();                                  // acquire
        double s[5];
        #pragma unroll
        for (int j = 0; j < 5; ++j) {
            // atomic read-with-add-0: device-coherent across XCD L2s
            double v = atomicAdd(&acc[j * ACC_BANKS + tid], 0.0);
            for (int off = 32; off > 0; off >>= 1) v += __shfl_down(v, off);
            s[j] = v;
        }
        if (tid == 0) {
            double Ninv = 1.0 / (double)cNTOT;
            double loss = s[0] * Ninv            // loss_x + loss_y
                        + 0.5 * s[1] * Ninv      // loss_w + loss_h
                        + 0.5 * s[2] * Ninv      // loss_conf
                        + s[3] / fmax(s[4], 1.0);// loss_cls
            out[0] = (float)loss;
        }
    }
}

extern "C" void kernel_launch(void* const* d_in, const int* in_sizes, int n_in,
                              void* d_out, int out_size, void* d_ws, size_t ws_size,
                              hipStream_t stream) {
    const float* output = (const float*)d_in[0];
    const float* target = (const float*)d_in[1];
    char* ws = (char*)d_ws;
    double* acc    = (double*)ws;
    int*    cnt    = (int*)(ws + OFF_CNT);
    int*    rowenc = (int*)(ws + OFF_ROW);

    hipMemsetAsync(ws, 0, ZERO_BYTES, stream);   // acc + cnt + rowenc

    k_main<<<cNB, 512, 0, stream>>>(output, target, rowenc, acc);
    k_cls<<<cCLS_BLOCKS, 192, 0, stream>>>(output, target, rowenc, acc, cnt, (float*)d_out);
}